// Round 9
// baseline (720.555 us; speedup 1.0000x reference)
//
#include <hip/hip_runtime.h>

typedef unsigned short u16;
typedef unsigned int   u32;
typedef __bf16  bf16x8 __attribute__((ext_vector_type(8)));
typedef float   f32x4  __attribute__((ext_vector_type(4)));
typedef u32     u32x4  __attribute__((ext_vector_type(4)));

#define NN 65536      // nodes
#define NE 524288     // edges
#define FD 256        // feature dim

typedef const __attribute__((address_space(1))) void* gas_p;
typedef __attribute__((address_space(3))) void* las_p;
#define GLDS16(g, l) __builtin_amdgcn_global_load_lds((gas_p)(const void*)(g), (las_p)(void*)(l), 16, 0, 0)

__device__ __forceinline__ u16 f2bf(float f){
  u32 u = __float_as_uint(f);
  u += 0x7fffu + ((u >> 16) & 1u);
  return (u16)(u >> 16);
}
__device__ __forceinline__ float bf2f(u32 lo16){
  return __uint_as_float(lo16 << 16);
}
__device__ __forceinline__ void acc8(float* a, uint4 v){
  a[0] += bf2f(v.x & 0xffffu); a[1] += bf2f(v.x >> 16);
  a[2] += bf2f(v.y & 0xffffu); a[3] += bf2f(v.y >> 16);
  a[4] += bf2f(v.z & 0xffffu); a[5] += bf2f(v.z >> 16);
  a[6] += bf2f(v.w & 0xffffu); a[7] += bf2f(v.w >> 16);
}

// ---------------- weight prep: fp32 (K,N=256) -> bf16 transposed (N=256,K) ----
__global__ __launch_bounds__(256) void prep_k(
    const float* __restrict__ w1a, const float* __restrict__ w1b,
    const float* __restrict__ w2a, const float* __restrict__ w2b,
    const float* __restrict__ w3a, const float* __restrict__ w3b,
    const float* __restrict__ w4a, const float* __restrict__ w4b,
    const float* __restrict__ wc1, u16* __restrict__ wT)
{
  int idx = blockIdx.x * 256 + threadIdx.x;   // 0 .. 655359
  const float* src; int base, K, local;
  if (idx < 131072){ src = w1a; base = 0; K = 512; local = idx; }
  else {
    local = idx - 131072;
    int j = local >> 16;       // 0..7
    local &= 65535;
    K = 256;
    base = 131072 + j * 65536;
    switch (j){
      case 0: src = w1b; break;
      case 1: src = w2a; break;
      case 2: src = w2b; break;
      case 3: src = w3a; break;
      case 4: src = w3b; break;
      case 5: src = w4a; break;
      case 6: src = w4b; break;
      default: src = wc1; break;
    }
  }
  int n = local & 255;
  int k = local >> 8;
  wT[base + n * K + k] = f2bf(src[k * 256 + n]);
}

// ---------------- CSR build ----------------
__global__ __launch_bounds__(256) void hist_k(const int* __restrict__ dst, int* __restrict__ deg){
  int e = blockIdx.x * 256 + threadIdx.x;
  atomicAdd(&deg[dst[e]], 1);
}

__global__ __launch_bounds__(1024) void scan_k(const int* __restrict__ deg, int* __restrict__ rs){
  __shared__ int part[1024];
  int t = threadIdx.x;
  int base = t * 64;
  int sum = 0;
  for (int i = 0; i < 64; ++i) sum += deg[base + i];
  part[t] = sum;
  __syncthreads();
  for (int off = 1; off < 1024; off <<= 1){
    int v = 0;
    if (t >= off) v = part[t - off];
    __syncthreads();
    part[t] += v;
    __syncthreads();
  }
  int run = part[t] - sum;          // exclusive prefix
  for (int i = 0; i < 64; ++i){ rs[base + i] = run; run += deg[base + i]; }
  if (t == 1023) rs[65536] = part[1023];
}

__global__ __launch_bounds__(256) void scat_k(
    const int* __restrict__ src, const int* __restrict__ dst,
    const int* __restrict__ rs, int* __restrict__ cursor, int* __restrict__ csr)
{
  int e = blockIdx.x * 256 + threadIdx.x;
  int d = dst[e];
  int pos = atomicAdd(&cursor[d], 1);
  csr[rs[d] + pos] = src[e];
}

// ------------- entry MFMA GEMM (R6-proven): C[M,256] = A[M,512] @ B ----------
// Tile 128 x 256 per block, 512 threads = 8 waves of 64x64. BK=64.
// A fp32 staged via VGPR convert; B via async global_load_lds. __syncthreads.
template<int K>
__global__ __launch_bounds__(512) void gemm512_k(
    const float* __restrict__ Af, const u16* __restrict__ Bt,
    u16* __restrict__ C)
{
  __shared__ u16 lds[32768];           // staging 48 KB?? -> 64 KB region: 32768 u16
  u16* As = lds;                       // 1024 chunks (128 rows x 8), swizzled
  u16* Bs = lds + 8192;                // 2048 chunks (256 rows x 8), swizzled
  const int t    = threadIdx.x;
  const int lane = t & 63;
  const int w    = t >> 6;             // 0..7
  const int wm   = w & 1;
  const int wn   = w >> 1;
  const int m0   = blockIdx.x * 128;
  const int mrow = lane & 15;
  const int quad = lane >> 4;

  f32x4 acc[4][4];
  const f32x4 zero = {0.f, 0.f, 0.f, 0.f};
  #pragma unroll
  for (int i = 0; i < 4; ++i)
    #pragma unroll
    for (int j = 0; j < 4; ++j) acc[i][j] = zero;

  for (int k0 = 0; k0 < K; k0 += 64){
    #pragma unroll
    for (int i = 0; i < 2; ++i){
      int p   = i * 512 + t;
      int row = p >> 3;
      const float* s = Af + (size_t)(m0 + row) * K + k0 + (p & 7) * 8;
      float4 x0 = *(const float4*)s;
      float4 x1 = *(const float4*)(s + 4);
      union { u32x4 q; u16 h[8]; } u;
      u.h[0] = f2bf(x0.x); u.h[1] = f2bf(x0.y); u.h[2] = f2bf(x0.z); u.h[3] = f2bf(x0.w);
      u.h[4] = f2bf(x1.x); u.h[5] = f2bf(x1.y); u.h[6] = f2bf(x1.z); u.h[7] = f2bf(x1.w);
      int dst = (p & ~7) | ((p & 7) ^ (row & 7));
      *(u32x4*)&As[dst * 8] = u.q;
    }
    #pragma unroll
    for (int i = 0; i < 4; ++i){
      int p   = i * 512 + t;
      int row = p >> 3;
      int ch  = (p & 7) ^ (row & 7);
      GLDS16(Bt + (size_t)row * K + k0 + ch * 8, &Bs[p * 8]);
    }
    __syncthreads();
    #pragma unroll
    for (int ks = 0; ks < 2; ++ks){
      bf16x8 af[4], bq[4];
      #pragma unroll
      for (int mi = 0; mi < 4; ++mi){
        int r  = wm * 64 + mi * 16 + mrow;
        int ch = (quad + ks * 4) ^ (r & 7);
        af[mi] = *(const bf16x8*)&As[(r * 8 + ch) * 8];
      }
      #pragma unroll
      for (int ni = 0; ni < 4; ++ni){
        int rb = wn * 64 + ni * 16 + mrow;
        int ch = (quad + ks * 4) ^ (rb & 7);
        bq[ni] = *(const bf16x8*)&Bs[(rb * 8 + ch) * 8];
      }
      #pragma unroll
      for (int mi = 0; mi < 4; ++mi)
        #pragma unroll
        for (int ni = 0; ni < 4; ++ni)
          acc[mi][ni] = __builtin_amdgcn_mfma_f32_16x16x32_bf16(af[mi], bq[ni], acc[mi][ni], 0, 0, 0);
    }
    __syncthreads();
  }

  // epilogue: acc -> LDS (128x256 u16) -> coalesced 16B stores
  #pragma unroll
  for (int ni = 0; ni < 4; ++ni){
    int c = wn * 64 + ni * 16 + mrow;
    #pragma unroll
    for (int mi = 0; mi < 4; ++mi){
      int rbase = wm * 64 + mi * 16 + quad * 4;
      #pragma unroll
      for (int reg = 0; reg < 4; ++reg)
        lds[(rbase + reg) * 256 + c] = f2bf(acc[mi][ni][reg]);
    }
  }
  __syncthreads();
  #pragma unroll
  for (int i = 0; i < 8; ++i){
    int p  = i * 512 + t;
    int r  = p >> 5;
    int ch = p & 31;
    u32x4 q = *(const u32x4*)&lds[r * 256 + ch * 8];
    *(u32x4*)&C[(size_t)(m0 + r) * 256 + ch * 8] = q;
  }
}

// ---- fused layer kernel: per 64-row tile (full N=256):
//  A) T = relu((1+eps)*y + sum_nbr y + ba)      (gather-agg into LDS)
//  B) acc1 = T @ WbT   (A-frags from LDS, B-frags direct from L2-hot weights)
//  C) X = BN(acc1)(+relu if RELU1) -> same LDS
//  D) acc2 = X @ W2T
//  E) epilogue2 (plain or PReLU if MODE2==2) -> LDS -> coalesced global store
// LDS layout: [64 rows][32 chunks of 8 u16], chunk pos = kc ^ (row & 7).
template<int GATH, int RELU1, int MODE2>
__global__ __launch_bounds__(256) void fused_k(
    const u16* __restrict__ y,
    const int* __restrict__ rs, const int* __restrict__ csr,
    const float* __restrict__ epsp, const float* __restrict__ ba,
    const u16* __restrict__ WbT,
    const float* __restrict__ g, const float* __restrict__ be,
    const float* __restrict__ bm, const float* __restrict__ bv,
    const float* __restrict__ bb,
    const u16* __restrict__ W2T,
    const float* __restrict__ q0, const float* __restrict__ q1,
    const int* __restrict__ gidx,
    u16* __restrict__ out)
{
  __shared__ u16 T[16384];             // 32 KB
  const int t    = threadIdx.x;
  const int lane = t & 63;
  const int wv   = t >> 6;             // 0..3
  const int m0   = blockIdx.x * 64;
  const int mrow = lane & 15;
  const int quad = lane >> 4;

  // ---- phase A: gather-aggregate into T ----
  {
    int sub = t >> 5, lane32 = t & 31;
    int f0 = lane32 * 8;
    float e1 = 1.0f + epsp[0];
    float4 b0 = *(const float4*)(ba + f0);
    float4 b1 = *(const float4*)(ba + f0 + 4);
    for (int rr = 0; rr < 8; ++rr){
      int row = sub * 8 + rr;
      int idx = m0 + row;
      int node = GATH ? (idx / 200) * 2048 + gidx[idx] : idx;
      int s0 = rs[node], s1 = rs[node + 1];
      float a[8] = {0.f,0.f,0.f,0.f,0.f,0.f,0.f,0.f};
      int e = s0;
      for (; e + 4 <= s1; e += 4){
        int sa = csr[e], sb = csr[e+1], sc = csr[e+2], sd = csr[e+3];
        uint4 va = *(const uint4*)(y + (size_t)sa * 256 + f0);
        uint4 vb = *(const uint4*)(y + (size_t)sb * 256 + f0);
        uint4 vc = *(const uint4*)(y + (size_t)sc * 256 + f0);
        uint4 vd = *(const uint4*)(y + (size_t)sd * 256 + f0);
        acc8(a, va); acc8(a, vb); acc8(a, vc); acc8(a, vd);
      }
      for (; e < s1; ++e)
        acc8(a, *(const uint4*)(y + (size_t)csr[e] * 256 + f0));
      uint4 own = *(const uint4*)(y + (size_t)node * 256 + f0);
      float r0 = fmaxf(e1 * bf2f(own.x & 0xffffu) + a[0] + b0.x, 0.f);
      float r1 = fmaxf(e1 * bf2f(own.x >> 16)     + a[1] + b0.y, 0.f);
      float r2 = fmaxf(e1 * bf2f(own.y & 0xffffu) + a[2] + b0.z, 0.f);
      float r3 = fmaxf(e1 * bf2f(own.y >> 16)     + a[3] + b0.w, 0.f);
      float r4 = fmaxf(e1 * bf2f(own.z & 0xffffu) + a[4] + b1.x, 0.f);
      float r5 = fmaxf(e1 * bf2f(own.z >> 16)     + a[5] + b1.y, 0.f);
      float r6 = fmaxf(e1 * bf2f(own.w & 0xffffu) + a[6] + b1.z, 0.f);
      float r7 = fmaxf(e1 * bf2f(own.w >> 16)     + a[7] + b1.w, 0.f);
      u32x4 o;
      o.x = (u32)f2bf(r0) | ((u32)f2bf(r1) << 16);
      o.y = (u32)f2bf(r2) | ((u32)f2bf(r3) << 16);
      o.z = (u32)f2bf(r4) | ((u32)f2bf(r5) << 16);
      o.w = (u32)f2bf(r6) | ((u32)f2bf(r7) << 16);
      int pos = row * 32 + (lane32 ^ (row & 7));
      *(u32x4*)&T[pos * 8] = o;
    }
  }
  __syncthreads();

  f32x4 acc[4][4];
  const f32x4 zero = {0.f, 0.f, 0.f, 0.f};
  #pragma unroll
  for (int i = 0; i < 4; ++i)
    #pragma unroll
    for (int j = 0; j < 4; ++j) acc[i][j] = zero;

  // ---- phase B: acc = T @ WbT (no barriers in K-loop) ----
  #pragma unroll
  for (int ks = 0; ks < 8; ++ks){
    bf16x8 af[4], bq[4];
    #pragma unroll
    for (int mi = 0; mi < 4; ++mi){
      int r  = mi * 16 + mrow;
      int kc = (ks * 4 + quad) ^ (r & 7);
      af[mi] = *(const bf16x8*)&T[(r * 32 + kc) * 8];
    }
    #pragma unroll
    for (int ni = 0; ni < 4; ++ni)
      bq[ni] = *(const bf16x8*)(WbT + (size_t)(wv * 64 + ni * 16 + mrow) * 256 + ks * 32 + quad * 8);
    #pragma unroll
    for (int mi = 0; mi < 4; ++mi)
      #pragma unroll
      for (int ni = 0; ni < 4; ++ni)
        acc[mi][ni] = __builtin_amdgcn_mfma_f32_16x16x32_bf16(af[mi], bq[ni], acc[mi][ni], 0, 0, 0);
  }
  __syncthreads();               // all T reads complete

  // ---- phase C: X = BN(acc) (+relu) -> T ----
  #pragma unroll
  for (int ni = 0; ni < 4; ++ni){
    int c = wv * 64 + ni * 16 + mrow;
    float s  = g[c] * rsqrtf(bv[c] + 1e-5f);
    float sh = (bb[c] - bm[c]) * s + be[c];
    int kc = c >> 3, lo = c & 7;
    #pragma unroll
    for (int mi = 0; mi < 4; ++mi){
      int rb = mi * 16 + quad * 4;
      #pragma unroll
      for (int reg = 0; reg < 4; ++reg){
        int r = rb + reg;
        float val = acc[mi][ni][reg] * s + sh;
        if (RELU1) val = fmaxf(val, 0.f);
        T[(r * 32 + (kc ^ (r & 7))) * 8 + lo] = f2bf(val);
      }
    }
  }
  __syncthreads();

  // ---- phase D: acc = X @ W2T ----
  #pragma unroll
  for (int i = 0; i < 4; ++i)
    #pragma unroll
    for (int j = 0; j < 4; ++j) acc[i][j] = zero;
  #pragma unroll
  for (int ks = 0; ks < 8; ++ks){
    bf16x8 af[4], bq[4];
    #pragma unroll
    for (int mi = 0; mi < 4; ++mi){
      int r  = mi * 16 + mrow;
      int kc = (ks * 4 + quad) ^ (r & 7);
      af[mi] = *(const bf16x8*)&T[(r * 32 + kc) * 8];
    }
    #pragma unroll
    for (int ni = 0; ni < 4; ++ni)
      bq[ni] = *(const bf16x8*)(W2T + (size_t)(wv * 64 + ni * 16 + mrow) * 256 + ks * 32 + quad * 8);
    #pragma unroll
    for (int mi = 0; mi < 4; ++mi)
      #pragma unroll
      for (int ni = 0; ni < 4; ++ni)
        acc[mi][ni] = __builtin_amdgcn_mfma_f32_16x16x32_bf16(af[mi], bq[ni], acc[mi][ni], 0, 0, 0);
  }
  __syncthreads();               // all X reads complete

  // ---- phase E: epilogue2 -> T -> coalesced global ----
  #pragma unroll
  for (int ni = 0; ni < 4; ++ni){
    int c = wv * 64 + ni * 16 + mrow;
    float sh = 0.f, sl = 0.f;
    if (MODE2 == 2){ sh = q0[c]; sl = q1[c]; }
    int kc = c >> 3, lo = c & 7;
    #pragma unroll
    for (int mi = 0; mi < 4; ++mi){
      int rb = mi * 16 + quad * 4;
      #pragma unroll
      for (int reg = 0; reg < 4; ++reg){
        int r = rb + reg;
        float val = acc[mi][ni][reg];
        if (MODE2 == 2){
          val += sh;
          val = val > 0.f ? val : sl * val;
        }
        T[(r * 32 + (kc ^ (r & 7))) * 8 + lo] = f2bf(val);
      }
    }
  }
  __syncthreads();
  #pragma unroll
  for (int i = 0; i < 8; ++i){
    int p  = i * 256 + t;        // 2048 chunks (64 rows x 32)
    int r  = p >> 5;
    int ch = p & 31;
    u32x4 q = *(const u32x4*)&T[(r * 32 + (ch ^ (r & 7))) * 8];
    *(u32x4*)&out[(size_t)(m0 + r) * 256 + ch * 8] = q;
  }
}

// ---------------- head: out[6400,2] = hc[6400,256] @ wc2[256,2] + bc2 ----------
__global__ __launch_bounds__(256) void head_k(
    const u16* __restrict__ hc, const float* __restrict__ wc2,
    const float* __restrict__ bc2, float* __restrict__ out)
{
  int row  = blockIdx.x * 4 + (threadIdx.x >> 6);
  int lane = threadIdx.x & 63;
  int f0   = lane * 4;
  uint2 hv = *(const uint2*)(hc + (size_t)row * 256 + f0);
  float h0 = bf2f(hv.x & 0xffffu), h1 = bf2f(hv.x >> 16);
  float h2 = bf2f(hv.y & 0xffffu), h3 = bf2f(hv.y >> 16);
  float4 wa = *(const float4*)(wc2 + f0 * 2);
  float4 wb = *(const float4*)(wc2 + f0 * 2 + 4);
  float acc0 = h0 * wa.x + h1 * wa.z + h2 * wb.x + h3 * wb.z;
  float acc1 = h0 * wa.y + h1 * wa.w + h2 * wb.y + h3 * wb.w;
  #pragma unroll
  for (int off = 32; off > 0; off >>= 1){
    acc0 += __shfl_xor(acc0, off);
    acc1 += __shfl_xor(acc1, off);
  }
  if (lane == 0){
    out[row * 2]     = acc0 + bc2[0];
    out[row * 2 + 1] = acc1 + bc2[1];
  }
}

extern "C" void kernel_launch(void* const* d_in, const int* in_sizes, int n_in,
                              void* d_out, int out_size, void* d_ws, size_t ws_size,
                              hipStream_t stream)
{
  const float* feat = (const float*)d_in[0];
  const int*   A    = (const int*)d_in[1];
  const int*   h1id = (const int*)d_in[2];
  const float* eps[4] = {(const float*)d_in[4],  (const float*)d_in[13], (const float*)d_in[22], (const float*)d_in[31]};
  const float* wa [4] = {(const float*)d_in[5],  (const float*)d_in[14], (const float*)d_in[23], (const float*)d_in[32]};
  const float* ba [4] = {(const float*)d_in[6],  (const float*)d_in[15], (const float*)d_in[24], (const float*)d_in[33]};
  const float* wb [4] = {(const float*)d_in[7],  (const float*)d_in[16], (const float*)d_in[25], (const float*)d_in[34]};
  const float* bb [4] = {(const float*)d_in[8],  (const float*)d_in[17], (const float*)d_in[26], (const float*)d_in[35]};
  const float* g  [4] = {(const float*)d_in[9],  (const float*)d_in[18], (const float*)d_in[27], (const float*)d_in[36]};
  const float* be [4] = {(const float*)d_in[10], (const float*)d_in[19], (const float*)d_in[28], (const float*)d_in[37]};
  const float* m  [4] = {(const float*)d_in[11], (const float*)d_in[20], (const float*)d_in[29], (const float*)d_in[38]};
  const float* v  [4] = {(const float*)d_in[12], (const float*)d_in[21], (const float*)d_in[30], (const float*)d_in[39]};
  const float* wc1 = (const float*)d_in[40];
  const float* bc1 = (const float*)d_in[41];
  const float* pa  = (const float*)d_in[42];
  const float* wc2 = (const float*)d_in[43];
  const float* bc2 = (const float*)d_in[44];

  char* ws = (char*)d_ws;
  u16* wT     = (u16*)(ws + 0);            // 1,310,720 B
  int* deg    = (int*)(ws + 1310720);
  int* rs     = (int*)(ws + 1572864);
  int* cursor = (int*)(ws + 1835264);
  int* csr    = (int*)(ws + 2097408);
  u16* y0     = (u16*)(ws + 4194560);      // 32 MB
  u16* y1     = (u16*)(ws + 37748992);     // 32 MB
  u16* hc     = (u16*)(ws + 71303424);     // 3.2 MB

  u16* w1aT = wT;            // [256][512]
  u16* w1bT = wT + 131072;
  u16* w2aT = wT + 196608;
  u16* w2bT = wT + 262144;
  u16* w3aT = wT + 327680;
  u16* w3bT = wT + 393216;
  u16* w4aT = wT + 458752;
  u16* w4bT = wT + 524288;
  u16* wc1T = wT + 589824;

  hipMemsetAsync(deg, 0, 65536 * 4, stream);
  hipMemsetAsync(cursor, 0, 65536 * 4, stream);
  prep_k<<<2560, 256, 0, stream>>>(wa[0], wb[0], wa[1], wb[1], wa[2], wb[2], wa[3], wb[3], wc1, wT);
  hist_k<<<NE / 256, 256, 0, stream>>>(A + NE, deg);
  scan_k<<<1, 1024, 0, stream>>>(deg, rs);
  scat_k<<<NE / 256, 256, 0, stream>>>(A, A + NE, rs, cursor, csr);

  // entry: y0 = feat @ w1a (K=512, fp32 A)
  gemm512_k<512><<<512, 512, 0, stream>>>(feat, w1aT, y0);

  // fused layers 1..3: agg + (Wb,BN,relu) + (@Wa_next)
  fused_k<0,1,0><<<1024, 256, 0, stream>>>(y0, rs, csr, eps[0], ba[0], w1bT,
      g[0], be[0], m[0], v[0], bb[0], w2aT, nullptr, nullptr, nullptr, y1);
  fused_k<0,1,0><<<1024, 256, 0, stream>>>(y1, rs, csr, eps[1], ba[1], w2bT,
      g[1], be[1], m[1], v[1], bb[1], w3aT, nullptr, nullptr, nullptr, y0);
  fused_k<0,1,0><<<1024, 256, 0, stream>>>(y0, rs, csr, eps[2], ba[2], w3bT,
      g[2], be[2], m[2], v[2], bb[2], w4aT, nullptr, nullptr, nullptr, y1);

  // fused layer 4 on the 6400 gathered rows: agg_g + (w4b,BN) + (@wc1,PReLU)
  fused_k<1,0,2><<<100, 256, 0, stream>>>(y1, rs, csr, eps[3], ba[3], w4bT,
      g[3], be[3], m[3], v[3], bb[3], wc1T, bc1, pa, h1id, hc);

  head_k<<<1600, 256, 0, stream>>>(hc, wc2, bc2, (float*)d_out);

  (void)in_sizes; (void)n_in; (void)out_size; (void)ws_size;
}